// Round 17
// baseline (5353.341 us; speedup 1.0000x reference)
//
#include <hip/hip_runtime.h>
#include <hip/hip_bf16.h>
#include <string.h>

typedef __bf16 bf16;
typedef __attribute__((ext_vector_type(8))) __bf16 bf16x8;
typedef __attribute__((ext_vector_type(2))) __bf16 bf16x2;
typedef __attribute__((ext_vector_type(4))) float  f32x4;
typedef unsigned long long u64;
typedef unsigned char u8;

#define DEV __device__ __forceinline__

constexpr int V = 32000, E = 512, H = 512, L = 64, NB = 32, H2 = 1024, T = 64, SOS = 127;
constexpr int GE = 4 * H;
constexpr int NBLK = 256;        // decoder blocks; per-block logits partials

// ---- ws layout (bytes) ----
constexpr size_t OFF_GIN    = 0;                                  // f32 [2][T][NB][GE]
constexpr size_t SZ_GIN     = (size_t)2*T*NB*GE*4;
constexpr size_t OFF_ENCOUT = OFF_GIN + SZ_GIN;                   // bf16 [NB][L][H2]
constexpr size_t SZ_ENCOUT  = (size_t)NB*L*H2*2;
constexpr size_t OFF_ENCH   = OFF_ENCOUT + SZ_ENCOUT;             // bf16 [2][2][NB][H]
constexpr size_t SZ_ENCH    = (size_t)2*2*NB*H*2;
constexpr size_t OFF_DECH   = OFF_ENCH + SZ_ENCH;                 // bf16 [2][NB][H2]
constexpr size_t SZ_DECH    = (size_t)2*NB*H2*2;
constexpr size_t OFF_CAT2   = OFF_DECH + SZ_DECH;                 // bf16 [NB][2*H2]
constexpr size_t SZ_CAT2    = (size_t)NB*2*H2*2;
constexpr size_t OFF_COMB   = OFF_CAT2 + SZ_CAT2;                 // bf16 [NB][H2]
constexpr size_t SZ_COMB    = (size_t)NB*H2*2;
constexpr size_t OFF_HH     = OFF_COMB + SZ_COMB;                 // f32 [NB][4*H2]
constexpr size_t SZ_HH      = (size_t)NB*4*H2*4;
constexpr size_t OFF_PMAX   = OFF_HH + SZ_HH;                     // f32 [2][NBLK][NB] parity
constexpr size_t SZ_P       = (size_t)2*NBLK*NB*4;
constexpr size_t OFF_PSUM   = OFF_PMAX + SZ_P;
constexpr size_t OFF_PIDX   = OFF_PSUM + SZ_P;
constexpr size_t OFF_LOGZ   = OFF_PIDX + SZ_P;                    // f32 [T][NB]
constexpr size_t SZ_LOGZ    = (size_t)T*NB*4;
constexpr size_t OFF_WEFIH  = OFF_LOGZ + SZ_LOGZ;                 // bf16 [4H][E]
constexpr size_t SZ_WENC    = (size_t)GE*E*2;
constexpr size_t OFF_WEFHH  = OFF_WEFIH + SZ_WENC;
constexpr size_t OFF_WEBIH  = OFF_WEFHH + SZ_WENC;
constexpr size_t OFF_WEBHH  = OFF_WEBIH + SZ_WENC;
constexpr size_t OFF_WCOMB  = OFF_WEBHH + SZ_WENC;                // bf16 [H2][2*H2]
constexpr size_t SZ_WCOMB   = (size_t)H2*2*H2*2;
constexpr size_t OFF_WDIH   = OFF_WCOMB + SZ_WCOMB;               // bf16 [4*H2][H2]
constexpr size_t SZ_WDEC    = (size_t)4*H2*H2*2;
constexpr size_t OFF_WDHH   = OFF_WDIH + SZ_WDEC;                 // (unused now)
constexpr size_t OFF_WOUT   = OFF_WDHH + SZ_WDEC;                 // fp8 region (reuse 64MB)
constexpr size_t OFF_WOUT8  = OFF_WOUT;                           // u8 [V][1024] swizzled
constexpr size_t SZ_WOUT8   = (size_t)V*1024;
constexpr size_t OFF_WDHH8  = OFF_WOUT8 + SZ_WOUT8;               // u8 [4096][1024] swizzled
constexpr size_t SZ_WOUT    = (size_t)V*H2*2;
constexpr size_t OFF_WATTN  = OFF_WOUT + SZ_WOUT;                 // bf16 [L][2*H2]
constexpr size_t SZ_WATTN   = (size_t)L*2*H2*2;
constexpr size_t OFF_EMB2   = OFF_WATTN + SZ_WATTN;               // bf16 [T*NB][E]
constexpr size_t SZ_EMB2    = (size_t)T*NB*E*2;
constexpr size_t OFF_BAR    = OFF_EMB2 + SZ_EMB2;
// dataflow epoch tags (ints, 128B apart):
constexpr int TAG_PT = 0, TAG_C2 = 8192, TAG_CB = 9216, TAG_H = 11264, TAG_E = 13312;
constexpr int TAG_TE = 15360;      // token/e-half-of-cat2 ready (32 lines)
constexpr int BAR_INTS = 16384;
constexpr size_t OFF_H8 = OFF_BAR + 131072;                       // u8 [32][1024] (h fp8)

// ---- decoder shared-memory layout ----
constexpr int SM_HL   = 114688;   // u8 [32][1024] swizzled h fp8 / D reduce scratch
constexpr int SM_CATF = 114688;   // f32[2048]  -> ends 122880
constexpr int SM_REDM = 122880;   // f32[512]
constexpr int SM_REDS = 124928;   // f32[512]
constexpr int SM_REDI = 126976;   // int[512]
constexpr int SM_SCR  = 129024;   // f32[4096]  -> ends 145408
constexpr int SM_BYTES = 147456;

DEV f32x4 mfma16(bf16x8 a, bf16x8 b, f32x4 c) {
  return __builtin_amdgcn_mfma_f32_16x16x32_bf16(a, b, c, 0, 0, 0);
}
DEV f32x4 mfma8(long a, long b, f32x4 c) {
  return __builtin_amdgcn_mfma_f32_16x16x32_fp8_fp8(a, b, c, 0, 0, 0);
}
DEV float sigm(float x) { return 1.f / (1.f + __expf(-x)); }
DEV bf16x8 ld8(const bf16* p) { return *(const bf16x8*)p; }

// ---------- device-scope (uncached) accessors for cross-block data ----------
union U16 { u64 u[2]; bf16x8 v8; f32x4 f4; };
union U4  { unsigned int u; bf16x2 v2; float f; };

DEV bf16x8 ld8_dev(const bf16* p) {
  U16 r;
  r.u[0] = __hip_atomic_load((const u64*)p,       __ATOMIC_RELAXED, __HIP_MEMORY_SCOPE_AGENT);
  r.u[1] = __hip_atomic_load((const u64*)(p + 4), __ATOMIC_RELAXED, __HIP_MEMORY_SCOPE_AGENT);
  return r.v8;
}
DEV void st8_dev(bf16* p, bf16x8 v) {
  U16 r; r.v8 = v;
  __hip_atomic_store((u64*)p,       r.u[0], __ATOMIC_RELAXED, __HIP_MEMORY_SCOPE_AGENT);
  __hip_atomic_store((u64*)(p + 4), r.u[1], __ATOMIC_RELAXED, __HIP_MEMORY_SCOPE_AGENT);
}
DEV void st16f_dev(float* p, f32x4 v) {
  U16 r; r.f4 = v;
  __hip_atomic_store((u64*)p,       r.u[0], __ATOMIC_RELAXED, __HIP_MEMORY_SCOPE_AGENT);
  __hip_atomic_store((u64*)(p + 2), r.u[1], __ATOMIC_RELAXED, __HIP_MEMORY_SCOPE_AGENT);
}
DEV float ldf_dev(const float* p) {
  return __hip_atomic_load(p, __ATOMIC_RELAXED, __HIP_MEMORY_SCOPE_AGENT);
}
DEV void stf_dev(float* p, float v) {
  __hip_atomic_store(p, v, __ATOMIC_RELAXED, __HIP_MEMORY_SCOPE_AGENT);
}
DEV int ldi_dev(const int* p) {
  return __hip_atomic_load(p, __ATOMIC_RELAXED, __HIP_MEMORY_SCOPE_AGENT);
}
DEV void sti_dev(int* p, int v) {
  __hip_atomic_store(p, v, __ATOMIC_RELAXED, __HIP_MEMORY_SCOPE_AGENT);
}
DEV void stb_dev(bf16* p, float x) {
  bf16 h = (bf16)x; unsigned short s; memcpy(&s, &h, 2);
  __hip_atomic_store((unsigned short*)p, s, __ATOMIC_RELAXED, __HIP_MEMORY_SCOPE_AGENT);
}
DEV void st2b_dev(bf16* p, bf16x2 v) {
  U4 r; r.v2 = v;
  __hip_atomic_store((unsigned int*)p, r.u, __ATOMIC_RELAXED, __HIP_MEMORY_SCOPE_AGENT);
}
DEV void stb8_dev(u8* p, u8 v) {
  __hip_atomic_store(p, v, __ATOMIC_RELAXED, __HIP_MEMORY_SCOPE_AGENT);
}
DEV u64 ldu64_dev(const u8* p) {
  return __hip_atomic_load((const u64*)p, __ATOMIC_RELAXED, __HIP_MEMORY_SCOPE_AGENT);
}

// ---------- dataflow epoch tags: single-hop producer->consumer sync ----------
DEV void tpub(int* tags, int slot, int ep) {
  __syncthreads();
  if (threadIdx.x == 0)
    sti_dev(tags + slot*32, ep);
}
DEV void twait(int* tags, int n, int ep) {
  if ((int)threadIdx.x < n)
    while (ldi_dev(tags + threadIdx.x*32) < ep)
      __builtin_amdgcn_s_sleep(1);
  asm volatile("" ::: "memory");
  __syncthreads();
}
// wave-scoped wait: lanes poll, no block sync (caller must sync before any
// cross-wave data interchange)
DEV void twait_wave(int* tags, int n, int ep) {
  int l = threadIdx.x & 63;
  if (l < n)
    while (ldi_dev(tags + l*32) < ep)
      __builtin_amdgcn_s_sleep(1);
  __builtin_amdgcn_wave_barrier();
  asm volatile("" ::: "memory");
}

// --------------------------------------- one-shot f32 -> bf16 conversions
struct ConvJobs { const float* src[7]; bf16* dst[7]; long n8[7]; };

__global__ __launch_bounds__(256) void k_convert_all(ConvJobs J) {
  long i0 = (long)blockIdx.x * 256 + threadIdx.x;
  long stride = (long)gridDim.x * 256;
  for (int j = 0; j < 7; ++j) {
    const float* __restrict__ src = J.src[j];
    bf16* __restrict__ dst = J.dst[j];
    long n8 = J.n8[j];
    for (long g = i0; g < n8; g += stride) {
      long o = g * 8;
      float4 a = *(const float4*)(src + o);
      float4 b = *(const float4*)(src + o + 4);
      bf16x8 v;
      v[0]=(bf16)a.x; v[1]=(bf16)a.y; v[2]=(bf16)a.z; v[3]=(bf16)a.w;
      v[4]=(bf16)b.x; v[5]=(bf16)b.y; v[6]=(bf16)b.z; v[7]=(bf16)b.w;
      *(bf16x8*)(dst + o) = v;
    }
  }
}

// ---- f32 -> fp8 e4m3 (x8 scale), XOR-swizzled 16B granules ----
__global__ __launch_bounds__(256) void k_conv_fp8(const float* __restrict__ wsrc,
                                                  const float* __restrict__ hsrc,
                                                  u8* __restrict__ wdst,
                                                  u8* __restrict__ hdst) {
  const long G1 = (long)V*64, G2 = (long)4096*64;
  for (long id = (long)blockIdx.x*256 + threadIdx.x; id < G1 + G2;
       id += (long)gridDim.x*256) {
    const float* s; u8* d; long n, g;
    if (id < G1) { n = id >> 6; g = id & 63; s = wsrc + n*1024 + g*16;
                   d = wdst + n*1024 + ((g ^ (n & 7)) << 4); }
    else { long j = id - G1; n = j >> 6; g = j & 63; s = hsrc + n*1024 + g*16;
           d = hdst + n*1024 + ((g ^ (n & 7)) << 4); }
    unsigned int wv[4];
#pragma unroll
    for (int q = 0; q < 4; ++q) {
      float4 f = *(const float4*)(s + q*4);
      int lo = __builtin_amdgcn_cvt_pk_fp8_f32(f.x*8.f, f.y*8.f, 0, false);
      int hi = __builtin_amdgcn_cvt_pk_fp8_f32(f.z*8.f, f.w*8.f, 0, false);
      wv[q] = (lo & 0xFFFF) | (hi << 16);
    }
    *(uint4*)d = make_uint4(wv[0], wv[1], wv[2], wv[3]);
  }
}

__global__ __launch_bounds__(256) void k_gather_emb(const int* __restrict__ x,
                                                    const float* __restrict__ embed,
                                                    bf16* __restrict__ emb2) {
  int gid = blockIdx.x * 256 + threadIdx.x;
  int m = gid >> 6, k8 = (gid & 63) * 8;
  int b = m & 31, t = m >> 5;
  int tok = x[b * L + t];
  const float* src = embed + (long)tok * E + k8;
  float4 a = *(const float4*)src;
  float4 c = *(const float4*)(src + 4);
  bf16x8 v;
  v[0]=(bf16)a.x; v[1]=(bf16)a.y; v[2]=(bf16)a.z; v[3]=(bf16)a.w;
  v[4]=(bf16)c.x; v[5]=(bf16)c.y; v[6]=(bf16)c.z; v[7]=(bf16)c.w;
  *(bf16x8*)(emb2 + (long)m * E + k8) = v;
}

__global__ __launch_bounds__(256) void k_init(bf16* ench, bf16* dech, float* hh,
                                              int* bar) {
  int i = blockIdx.x * 256 + threadIdx.x;          // grid 512
  hh[i] = 0.f;
  if (i < 2*NB*H)  ench[i] = (bf16)0.f;
  if (i < NB*H2)   dech[i] = (bf16)0.f;
  if (i < BAR_INTS) bar[i] = 0;
}

// ------------------------------------------- encoder input gates (both dirs)
__global__ __launch_bounds__(256) void k_enc_ingemm(
    const bf16* __restrict__ emb2,
    const bf16* __restrict__ fWih, const float* __restrict__ fB,
    const bf16* __restrict__ bWih, const float* __restrict__ bB,
    float* __restrict__ gin)
{
  int wid  = blockIdx.x * 4 + (threadIdx.x >> 6);
  int lane = threadIdx.x & 63;
  int dir  = wid >> 11;
  int w2   = wid & 2047;
  int m0   = (w2 >> 5) * 32;
  int n0   = (w2 & 31) * 64;
  const bf16*  Wih  = dir ? bWih : fWih;
  const float* Bias = dir ? bB : fB;
  int col = lane & 15, kq = lane >> 4, r4 = kq * 4;

  const bf16* arow[4];
#pragma unroll
  for (int nt = 0; nt < 4; ++nt) arow[nt] = Wih + (long)(n0 + nt*16 + col)*E + kq*8;
  const bf16* brow[2];
#pragma unroll
  for (int mt = 0; mt < 2; ++mt) brow[mt] = emb2 + (long)(m0 + mt*16 + col)*E + kq*8;

  f32x4 acc[2][4] = {};
  for (int kk = 0; kk < E/32; ++kk) {
    bf16x8 a[4], bv[2];
#pragma unroll
    for (int nt = 0; nt < 4; ++nt) a[nt] = ld8(arow[nt] + kk*32);
#pragma unroll
    for (int mt = 0; mt < 2; ++mt) bv[mt] = ld8(brow[mt] + kk*32);
#pragma unroll
    for (int mt = 0; mt < 2; ++mt)
#pragma unroll
      for (int nt = 0; nt < 4; ++nt)
        acc[mt][nt] = mfma16(a[nt], bv[mt], acc[mt][nt]);
  }
#pragma unroll
  for (int mt = 0; mt < 2; ++mt) {
    int m = m0 + mt*16 + col;
    int b = m & 31, t = m >> 5;
    float* gp = gin + ((long)(dir*T + t)*NB + b)*GE;
#pragma unroll
    for (int nt = 0; nt < 4; ++nt) {
      int nb = n0 + nt*16 + r4;
      f32x4 v = acc[mt][nt];
      float4 o;
      o.x = v[0] + Bias[nb+0];
      o.y = v[1] + Bias[nb+1];
      o.z = v[2] + Bias[nb+2];
      o.w = v[3] + Bias[nb+3];
      *(float4*)(gp + nb) = o;
    }
  }
}

// ============================ persistent encoder =========================
struct EncArgs {
  const bf16* fWhh; const bf16* bWhh; const float* gin;
  bf16* ench; bf16* encout; int* etag;
};

__global__ __launch_bounds__(256, 1) void k_encoder(EncArgs A) {
  __shared__ float lds[4][16][32];
  int tid = threadIdx.x, w = tid >> 6, lane = tid & 63;
  int dir = blockIdx.x >> 5, j0 = (blockIdx.x & 31) * 16;
  int col = lane & 15, kq = lane >> 4, r4 = kq*4;
  const bf16* Whh = dir ? A.bWhh : A.fWhh;
  const bf16* arow = Whh + (long)(w*H + j0 + col)*H + kq*8;
  int* myTags = A.etag + dir*32*32;      // 32 same-dir tag lines
  float creg0 = 0.f, creg1 = 0.f;

  for (int t = 0; t < T; ++t) {
    if (t > 0) twait(myTags, 32, t);
    const bf16* hbase = A.ench + (t&1)*(2*NB*H) + dir*(NB*H);
    bf16*       hout  = A.ench + ((t&1)^1)*(2*NB*H) + dir*(NB*H);
    const bf16* b0 = hbase + col*H + kq*8;
    const bf16* b1 = hbase + (16+col)*H + kq*8;
    f32x4 a0 = {}, a1 = {};
    for (int kk = 0; kk < H/32; ++kk) {
      bf16x8 a = ld8(arow + kk*32);
      a0 = mfma16(a, ld8_dev(b0 + kk*32), a0);
      a1 = mfma16(a, ld8_dev(b1 + kk*32), a1);
    }
#pragma unroll
    for (int r = 0; r < 4; ++r) { lds[w][r4+r][col] = a0[r]; lds[w][r4+r][16+col] = a1[r]; }
    __syncthreads();
    const float* gp = A.gin + (long)(dir*T + t)*NB*GE;
    {
      int jj = tid >> 5, b = tid & 31, j = j0 + jj;
      const float* g4 = gp + (long)b*GE;
      float i_ = sigm(lds[0][jj][b] + g4[0*H + j]);
      float f_ = sigm(lds[1][jj][b] + g4[1*H + j]);
      float g_ = tanhf(lds[2][jj][b] + g4[2*H + j]);
      float o_ = sigm(lds[3][jj][b] + g4[3*H + j]);
      float c2 = f_*creg0 + i_*g_; creg0 = c2;
      float hv = o_*tanhf(c2);
      stb_dev(hout + b*H + j, hv);
      A.encout[((long)b*L + t)*H2 + dir*H + j] = (bf16)hv;
    }
    {
      int idx = tid + 256, jj = idx >> 5, b = idx & 31, j = j0 + jj;
      const float* g4 = gp + (long)b*GE;
      float i_ = sigm(lds[0][jj][b] + g4[0*H + j]);
      float f_ = sigm(lds[1][jj][b] + g4[1*H + j]);
      float g_ = tanhf(lds[2][jj][b] + g4[2*H + j]);
      float o_ = sigm(lds[3][jj][b] + g4[3*H + j]);
      float c2 = f_*creg1 + i_*g_; creg1 = c2;
      float hv = o_*tanhf(c2);
      stb_dev(hout + b*H + j, hv);
      A.encout[((long)b*L + t)*H2 + dir*H + j] = (bf16)hv;
    }
    tpub(myTags, blockIdx.x & 31, t + 1);
  }
}

// ============================ persistent decoder (512 thr) ================
struct DecArgs {
  const float* dec_embed; const bf16* wattn; const float* attn_b;
  const bf16* encout;
  const bf16* wcomb; const float* comb_b;
  const bf16* wdih; const float* db;
  const u8* wout8; const u8* wdhh8; const float* outb;
  bf16* dech; u8* hout8; float* hh; bf16* cat2; bf16* comb;
  float* pmax; float* psum; int* pidx; float* logz; float* out;
  int* tags;
};

__global__ __launch_bounds__(512, 1) void k_decoder(DecArgs A) {
  __shared__ __attribute__((aligned(16))) char smem[SM_BYTES];
  __shared__ float aw[64];
  __shared__ int   stok;
  float* catF = (float*)(smem + SM_CATF);
  float* redm = (float*)(smem + SM_REDM);
  float* reds = (float*)(smem + SM_REDS);
  int*   redi = (int*)  (smem + SM_REDI);
  float* scr  = (float*)(smem + SM_SCR);

  int* PT  = A.tags + TAG_PT;
  int* C2T = A.tags + TAG_C2;
  int* CBT = A.tags + TAG_CB;
  int* HT  = A.tags + TAG_H;
  int* TET = A.tags + TAG_TE;

  int tid = threadIdx.x, bid = blockIdx.x;
  int w = tid >> 6, lane = tid & 63;
  int col = lane & 15, kq = lane >> 4, r4 = kq*4;
  float creg = 0.f;                    // cell state (blocks 0..63)

  // -------- tile ownership: blocks 0-47: 8 tiles; 48-255: 9 tiles --------
  int ntot = (bid < 48) ? 8 : 9;
  int tstart = (bid < 48) ? bid*8 : 384 + 9*(bid - 48);
  const int nlds = 7;                  // all blocks keep 7 tiles in LDS

  // -------- one-time: fill LDS weight tiles (fp8, pre-swizzled global) ---
  for (int i = 0; i < nlds; ++i) {
    int tn = tstart + i;
    const u8* src = (tn < 2000) ? A.wout8 + (long)tn*16384
                                : A.wdhh8 + (long)(tn - 2000)*16384;
#pragma unroll
    for (int rr = 0; rr < 2; ++rr) {
      int flat = rr*8192 + w*1024 + lane*16;
      __builtin_amdgcn_global_load_lds(
          (const __attribute__((address_space(1))) void*)(src + flat),
          (__attribute__((address_space(3))) void*)(smem + i*16384 + rr*8192 + w*1024),
          16, 0, 0);
    }
  }
  // -------- one-time: streamed tile(s) -> registers (constant all steps) --
  // wave 7 serves tile tstart+7 (ti==7, ii==0); wave 0 serves tile tstart+8.
  u64 sreg[32];
  {
    int myTile = -1;
    if (w == 7 && ntot >= 8) myTile = tstart + 7;
    if (w == 0 && ntot == 9) myTile = tstart + 8;
    if (myTile >= 0) {
      const u8* Ab = ((myTile < 2000) ? A.wout8 + (long)myTile*16384
                                      : A.wdhh8 + (long)(myTile - 2000)*16384) + col*1024;
#pragma unroll
      for (int ks = 0; ks < 32; ++ks) {
        int off = (((ks*2 + (kq>>1)) ^ (col & 7)) << 4) + (kq & 1)*8;
        sreg[ks] = *(const u64*)(Ab + off);
      }
    } else {
#pragma unroll
      for (int ks = 0; ks < 32; ++ks) sreg[ks] = 0;
    }
  }
  asm volatile("s_waitcnt vmcnt(0)" ::: "memory");
  __syncthreads();

  for (int t = 0; t < T; ++t) {
    const bf16* hin  = A.dech + (t&1)*(NB*H2);
    bf16*       hout = A.dech + ((t&1)^1)*(NB*H2);
    float* pmaxP = A.pmax + ((t&1)^1)*NBLK*32;     // partials of step t-1
    float* psumP = A.psum + ((t&1)^1)*NBLK*32;
    int*   pidxP = A.pidx + ((t&1)^1)*NBLK*32;

    // ---------------- phase A: argmax(t-1) + attention + cat2 -------------
    if (bid < NB) {
      int b = bid;
      if (t > 0) {
        twait(PT, NBLK, t);
        float m = -1e30f, s = 0.f; int id = 0;
        if (tid < 256) {
          m  = ldf_dev(pmaxP + tid*32 + b);
          s  = ldf_dev(psumP + tid*32 + b);
          id = ldi_dev(pidxP + tid*32 + b);
#pragma unroll
          for (int off = 1; off < 64; off <<= 1) {
            float om = __shfl_xor(m, off);
            float os = __shfl_xor(s, off);
            int   oi = __shfl_xor(id, off);
            s += os;
            if (om > m || (om == m && oi < id)) { m = om; id = oi; }
          }
          if (lane == 0) { redm[w] = m; reds[w] = s; redi[w] = id; }
        }
        __syncthreads();
        if (tid == 0) {
          float mm = redm[0]; int ii2 = redi[0];
          float ss = reds[0] + reds[1] + reds[2] + reds[3];
#pragma unroll
          for (int q = 1; q < 4; ++q) {
            if (redm[q] > mm || (redm[q] == mm && redi[q] < ii2)) { mm = redm[q]; ii2 = redi[q]; }
          }
          A.logz[(t-1)*32 + b] = logf(ss);
          stok = ii2;
        }
      } else if (tid == 0) stok = SOS;
      __syncthreads();
      int tok = stok;

      const float* erow = A.dec_embed + (long)tok*H2;
      bf16* c2row = A.cat2 + (long)b*(2*H2);
      if (tid < 128) {
        int o = tid*8;
        float4 a = *(const float4*)(erow + o);
        float4 c = *(const float4*)(erow + o + 4);
        catF[o+0]=a.x; catF[o+1]=a.y; catF[o+2]=a.z; catF[o+3]=a.w;
        catF[o+4]=c.x; catF[o+5]=c.y; catF[o+6]=c.z; catF[o+7]=c.w;
        bf16x8 v;
        v[0]=(bf16)a.x; v[1]=(bf16)a.y; v[2]=(bf16)a.z; v[3]=(bf16)a.w;
        v[4]=(bf16)c.x; v[5]=(bf16)c.y; v[6]=(bf16)c.z; v[7]=(bf16)c.w;
        st8_dev(c2row + o, v);
      } else if (tid < 256) {
        int o = (tid - 128)*8;
        bf16x8 hv = ld8_dev(hin + (long)b*H2 + o);
#pragma unroll
        for (int e = 0; e < 8; ++e) catF[H2 + o + e] = (float)hv[e];
      }
      tpub(TET, bid, t + 1);   // e-half of cat2 published (includes syncthreads)

      {  // scores: 8 threads per l, K=256 each
        int l = tid >> 3, q = tid & 7;
        const bf16*  wrow = A.wattn + (long)l*(2*H2) + q*256;
        const float* crow = catF + q*256;
        float sacc = 0.f;
        for (int k = 0; k < 256; k += 8) {
          bf16x8 wv = ld8(wrow + k);
#pragma unroll
          for (int e = 0; e < 8; ++e) sacc += (float)wv[e] * crow[k+e];
        }
        sacc += __shfl_xor(sacc, 1);
        sacc += __shfl_xor(sacc, 2);
        sacc += __shfl_xor(sacc, 4);
        if (q == 0) aw[l] = sacc + A.attn_b[l];
      }
      __syncthreads();

      if (tid < 64) {  // softmax over L
        float v = aw[tid];
        float m = v;
#pragma unroll
        for (int off = 1; off < 64; off <<= 1) m = fmaxf(m, __shfl_xor(m, off));
        float p = __expf(v - m);
        float s = p;
#pragma unroll
        for (int off = 1; off < 64; off <<= 1) s += __shfl_xor(s, off);
        aw[tid] = p / s;
      }
      __syncthreads();

      {  // ctx: 4 l-groups x 128 threads x bf16x8
        int grp = tid >> 7, jt = tid & 127;
        int j8 = jt * 8;
        const bf16* eo = A.encout + (long)b*L*H2 + j8;
        float acc[8] = {};
        for (int l = grp*16; l < grp*16 + 16; ++l) {
          float a = aw[l];
          bf16x8 v = ld8(eo + (long)l*H2);
#pragma unroll
          for (int e = 0; e < 8; ++e) acc[e] += a*(float)v[e];
        }
#pragma unroll
        for (int e = 0; e < 8; ++e) scr[grp*1024 + j8 + e] = acc[e];
      }
      __syncthreads();
      {
        int j2 = tid * 2;
        bf16x2 o;
#pragma unroll
        for (int e = 0; e < 2; ++e) {
          int j = j2 + e;
          o[e] = (bf16)(scr[j] + scr[1024+j] + scr[2048+j] + scr[3072+j]);
        }
        st2b_dev(c2row + H2 + j2, o);
      }
      tpub(C2T, bid, t + 1);
    }

    // ---------------- phase B: comb = relu(cat2@Wc.T + b) ----------------
    // waves 0-3 consume the e-half (ready at TET, mid-A); waves 4-7 the
    // ctx-half (ready at C2T). Wave-scoped waits; block sync before reduce.
    if (bid < 64) {
      if (w < 4) twait_wave(TET, 32, t + 1);
      else       twait_wave(C2T, 32, t + 1);
      int n0 = bid * 16;
      const bf16* arow = A.wcomb + (long)(n0 + col)*(2*H2) + w*256 + kq*8;
      const bf16* b0 = A.cat2 + (long)col*(2*H2) + w*256 + kq*8;
      const bf16* b1 = A.cat2 + (long)(16+col)*(2*H2) + w*256 + kq*8;
      f32x4 a0 = {}, a1 = {};
      for (int kk = 0; kk < 8; ++kk) {
        bf16x8 a = ld8(arow + kk*32);
        a0 = mfma16(a, ld8_dev(b0 + kk*32), a0);
        a1 = mfma16(a, ld8_dev(b1 + kk*32), a1);
      }
#pragma unroll
      for (int r = 0; r < 4; ++r) {
        scr[(w*2+0)*256 + (r4+r)*16 + col] = a0[r];
        scr[(w*2+1)*256 + (r4+r)*16 + col] = a1[r];
      }
      __syncthreads();
      {
        int r = tid >> 5, b = tid & 31;
        int bt = b >> 4, cb = b & 15;
        float v = 0.f;
#pragma unroll
        for (int g = 0; g < 8; ++g) v += scr[(g*2+bt)*256 + r*16 + cb];
        v += A.comb_b[n0 + r];
        stb_dev(A.comb + (long)b*H2 + n0 + r, fmaxf(v, 0.f));
      }
      tpub(CBT, bid, t + 1);
    }

    // ---------------- phase C: LSTM cell ----------------
    if (bid < 64) {
      twait(CBT, 64, t + 1);
      int j0 = bid * 16;
      int g = w >> 1, half = w & 1;
      const bf16* arow = A.wdih + (long)(g*H2 + j0 + col)*H2 + half*512 + kq*8;
      const bf16* b0 = A.comb + (long)col*H2 + half*512 + kq*8;
      const bf16* b1 = A.comb + (long)(16+col)*H2 + half*512 + kq*8;
      f32x4 a0 = {}, a1 = {};
      for (int kk = 0; kk < 16; ++kk) {
        bf16x8 a = ld8(arow + kk*32);
        a0 = mfma16(a, ld8_dev(b0 + kk*32), a0);
        a1 = mfma16(a, ld8_dev(b1 + kk*32), a1);
      }
#pragma unroll
      for (int r = 0; r < 4; ++r) {
        scr[(w*2+0)*256 + (r4+r)*16 + col] = a0[r];
        scr[(w*2+1)*256 + (r4+r)*16 + col] = a1[r];
      }
      __syncthreads();
      {
        int jj = tid >> 5, b = tid & 31, j = j0 + jj;
        int bt = b >> 4, cb = b & 15;
#define GV(gg) (scr[((2*(gg)+0)*2+bt)*256 + jj*16 + cb] + scr[((2*(gg)+1)*2+bt)*256 + jj*16 + cb] \
                + A.db[(gg)*H2 + j] + ldf_dev(A.hh + (long)b*(4*H2) + (gg)*H2 + j))
        float i_ = sigm(GV(0));
        float f_ = sigm(GV(1));
        float g_ = tanhf(GV(2));
        float o_ = sigm(GV(3));
#undef GV
        float c2 = f_*creg + i_*g_; creg = c2;
        float hv = o_*tanhf(c2);
        stb_dev(hout + b*H2 + j, hv);
        int q8 = __builtin_amdgcn_cvt_pk_fp8_f32(hv*16.f, hv*16.f, 0, false);
        stb8_dev(A.hout8 + b*1024 + j, (u8)(q8 & 0xFF));
      }
      tpub(HT, bid, t + 1);
    }

    // ----- phase D: logits/hh from LDS tiles + register tiles -------------
    {
      twait(HT, 64, t + 1);
      float* pmaxW = A.pmax + (t&1)*NBLK*32;       // partials of step t
      float* psumW = A.psum + (t&1)*NBLK*32;
      int*   pidxW = A.pidx + (t&1)*NBLK*32;

      // stage h fp8 -> LDS (swizzled); overwrites ABC scratch (dead now)
#pragma unroll
      for (int k2 = 0; k2 < 4; ++k2) {
        int id = k2*512 + tid;
        int r = id >> 6, g = id & 63;
        const u8* sp = A.hout8 + r*1024 + g*16;
        u64 lo = ldu64_dev(sp);
        u64 hi = ldu64_dev(sp + 8);
        char* dp = smem + SM_HL + r*1024 + ((g ^ (r & 7)) << 4);
        *(u64*)dp = lo; *(u64*)(dp + 8) = hi;
      }
      __syncthreads();

      float pm[2] = {-1e30f, -1e30f};
      float ps[2] = {0.f, 0.f};
      int  pid[2] = {0, 0};

      for (int ii = 0; ii < 2; ++ii) {
        if (ii == 1 && (w != 0 || ntot < 9)) break;
        int ti = (ii == 0) ? w : 8;
        int tn = tstart + ti;
        f32x4 acc0 = {}, acc1 = {};
        const char* Hb = smem + SM_HL + col*1024;
        if (ti < nlds) {
          const char* Ab = smem + ti*16384 + col*1024;
#pragma unroll 8
          for (int ks = 0; ks < 32; ++ks) {
            int off = (((ks*2 + (kq>>1)) ^ (col & 7)) << 4) + (kq & 1)*8;
            long a  = *(const long*)(Ab + off);
            long b0 = *(const long*)(Hb + off);
            long b1 = *(const long*)(Hb + 16*1024 + off);
            acc0 = mfma8(a, b0, acc0);
            acc1 = mfma8(a, b1, acc1);
          }
        } else {
          // register-resident tile (loaded once before t-loop)
#pragma unroll
          for (int ks = 0; ks < 32; ++ks) {
            int off = (((ks*2 + (kq>>1)) ^ (col & 7)) << 4) + (kq & 1)*8;
            long a  = (long)sreg[ks];
            long b0 = *(const long*)(Hb + off);
            long b1 = *(const long*)(Hb + 16*1024 + off);
            acc0 = mfma8(a, b0, acc0);
            acc1 = mfma8(a, b1, acc1);
          }
        }
        if (tn < 2000) {
          int nb = tn*16 + kq*4;
#pragma unroll
          for (int bt = 0; bt < 2; ++bt) {
            int b = col + bt*16;
            f32x4 v = bt ? acc1 : acc0;
            f32x4 o;
#pragma unroll
            for (int r = 0; r < 4; ++r) {
              float xv = v[r]*0.0078125f + A.outb[nb + r];
              o[r] = xv;
              ps[bt] += __expf(xv);
              if (xv > pm[bt]) { pm[bt] = xv; pid[bt] = nb + r; }
            }
            __builtin_nontemporal_store(o, (f32x4*)(A.out + ((long)b*T + t)*V + nb));
          }
        } else {
          int nb = (tn - 2000)*16 + kq*4;
#pragma unroll
          for (int bt = 0; bt < 2; ++bt) {
            int b = col + bt*16;
            f32x4 v = bt ? acc1 : acc0;
#pragma unroll
            for (int r = 0; r < 4; ++r) v[r] *= 0.0078125f;
            st16f_dev(A.hh + (long)b*(4*H2) + nb, v);
          }
        }
      }
      // wave-level reduce
#pragma unroll
      for (int off = 16; off <= 32; off <<= 1) {
#pragma unroll
        for (int bt = 0; bt < 2; ++bt) {
          float om = __shfl_xor(pm[bt], off);
          float os = __shfl_xor(ps[bt], off);
          int   oi = __shfl_xor(pid[bt], off);
          ps[bt] += os;
          if (om > pm[bt] || (om == pm[bt] && oi < pid[bt])) { pm[bt] = om; pid[bt] = oi; }
        }
      }
      // cross-wave reduce to ONE per-block partial (reuse SM_HL after h reads)
      __syncthreads();
      float* dm = (float*)(smem + SM_HL);
      float* ds = dm + 256;
      int*   di = (int*)(ds + 256);
      if (lane < 16) {
#pragma unroll
        for (int bt = 0; bt < 2; ++bt) {
          int b = bt*16 + lane;
          dm[w*32 + b] = pm[bt];
          ds[w*32 + b] = ps[bt];
          di[w*32 + b] = pid[bt];
        }
      }
      __syncthreads();
      if (tid < 32) {
        int b = tid;
        float m = -1e30f, s = 0.f; int id = 0;
#pragma unroll
        for (int r = 0; r < 8; ++r) {
          float om = dm[r*32 + b]; int oi = di[r*32 + b];
          s += ds[r*32 + b];
          if (om > m || (om == m && oi < id)) { m = om; id = oi; }
        }
        stf_dev(pmaxW + bid*32 + b, m);
        stf_dev(psumW + bid*32 + b, s);
        sti_dev(pidxW + bid*32 + b, id);
      }
      tpub(PT, bid, t + 1);
    }
  }

  // final logZ (step T-1): partials parity (T-1)&1 = 1
  if (bid < NB) {
    twait(PT, NBLK, T);
    int b = bid;
    const float* psumP = A.psum + ((T-1)&1)*NBLK*32;
    float s = 0.f;
    if (tid < 256) {
      s = ldf_dev(psumP + tid*32 + b);
#pragma unroll
      for (int off = 1; off < 64; off <<= 1) s += __shfl_xor(s, off);
      if (lane == 0) reds[w] = s;
    }
    __syncthreads();
    if (tid == 0) A.logz[(T-1)*32 + b] = logf(reds[0] + reds[1] + reds[2] + reds[3]);
  }
}

// ------------------------- final: out[b][t][v] = raw_logit - logZ[t][b]
__global__ __launch_bounds__(256) void k_fixup(float* __restrict__ out,
                                               const float* __restrict__ logz)
{
  long i = (long)blockIdx.x * 256 + threadIdx.x;
  long stride = (long)gridDim.x * 256;
  long total = (long)NB * T * V / 4;
  for (long g = i; g < total; g += stride) {
    long flat = g * 4;
    long bt = flat / V;
    int tt = (int)(bt & 63), b = (int)(bt >> 6);
    float lz = logz[tt*32 + b];
    f32x4 v = *(const f32x4*)(out + flat);
    v[0] -= lz; v[1] -= lz; v[2] -= lz; v[3] -= lz;
    __builtin_nontemporal_store(v, (f32x4*)(out + flat));
  }
}

extern "C" void kernel_launch(void* const* d_in, const int* in_sizes, int n_in,
                              void* d_out, int out_size, void* d_ws, size_t ws_size,
                              hipStream_t stream)
{
  const int*   x         = (const int*)  d_in[0];
  const float* enc_embed = (const float*)d_in[1];
  const float* ef_Wih    = (const float*)d_in[2];
  const float* ef_Whh    = (const float*)d_in[3];
  const float* ef_b      = (const float*)d_in[4];
  const float* eb_Wih    = (const float*)d_in[5];
  const float* eb_Whh    = (const float*)d_in[6];
  const float* eb_b      = (const float*)d_in[7];
  const float* dec_embed = (const float*)d_in[8];
  const float* attn_W    = (const float*)d_in[9];
  const float* attn_b    = (const float*)d_in[10];
  const float* comb_W    = (const float*)d_in[11];
  const float* comb_b    = (const float*)d_in[12];
  const float* d_Wih     = (const float*)d_in[13];
  const float* d_Whh     = (const float*)d_in[14];
  const float* d_b       = (const float*)d_in[15];
  const float* out_W     = (const float*)d_in[16];
  const float* out_b     = (const float*)d_in[17];
  float* out = (float*)d_out;
  char* ws = (char*)d_ws;

  float* gin    = (float*)(ws + OFF_GIN);
  bf16*  encout = (bf16*) (ws + OFF_ENCOUT);
  bf16*  ench   = (bf16*) (ws + OFF_ENCH);
  bf16*  dech   = (bf16*) (ws + OFF_DECH);
  bf16*  cat2   = (bf16*) (ws + OFF_CAT2);
  bf16*  comb   = (bf16*) (ws + OFF_COMB);
  float* hh     = (float*)(ws + OFF_HH);
  float* pmax   = (float*)(ws + OFF_PMAX);
  float* psum   = (float*)(ws + OFF_PSUM);
  int*   pidx   = (int*)  (ws + OFF_PIDX);
  float* logz   = (float*)(ws + OFF_LOGZ);
  bf16*  wefih  = (bf16*) (ws + OFF_WEFIH);
  bf16*  wefhh  = (bf16*) (ws + OFF_WEFHH);
  bf16*  webih  = (bf16*) (ws + OFF_WEBIH);
  bf16*  webhh  = (bf16*) (ws + OFF_WEBHH);
  bf16*  wcomb  = (bf16*) (ws + OFF_WCOMB);
  bf16*  wdih   = (bf16*) (ws + OFF_WDIH);
  u8*    wout8  = (u8*)   (ws + OFF_WOUT8);
  u8*    wdhh8  = (u8*)   (ws + OFF_WDHH8);
  bf16*  wattn  = (bf16*) (ws + OFF_WATTN);
  bf16*  emb2   = (bf16*) (ws + OFF_EMB2);
  int*   bar    = (int*)  (ws + OFF_BAR);
  u8*    hout8  = (u8*)   (ws + OFF_H8);

  ConvJobs J;
  J.src[0]=ef_Wih; J.dst[0]=wefih; J.n8[0]=(long)GE*E/8;
  J.src[1]=ef_Whh; J.dst[1]=wefhh; J.n8[1]=(long)GE*H/8;
  J.src[2]=eb_Wih; J.dst[2]=webih; J.n8[2]=(long)GE*E/8;
  J.src[3]=eb_Whh; J.dst[3]=webhh; J.n8[3]=(long)GE*H/8;
  J.src[4]=comb_W; J.dst[4]=wcomb; J.n8[4]=(long)H2*2*H2/8;
  J.src[5]=d_Wih;  J.dst[5]=wdih;  J.n8[5]=(long)4*H2*H2/8;
  J.src[6]=attn_W; J.dst[6]=wattn; J.n8[6]=(long)L*2*H2/8;
  hipLaunchKernelGGL(k_convert_all, dim3(2048), dim3(256), 0, stream, J);
  hipLaunchKernelGGL(k_conv_fp8, dim3(2048), dim3(256), 0, stream,
                     out_W, d_Whh, wout8, wdhh8);
  hipLaunchKernelGGL(k_gather_emb, dim3(512), dim3(256), 0, stream, x, enc_embed, emb2);
  hipLaunchKernelGGL(k_init, dim3(512), dim3(256), 0, stream, ench, dech, hh, bar);
  hipLaunchKernelGGL(k_enc_ingemm, dim3(1024), dim3(256), 0, stream,
                     emb2, wefih, ef_b, webih, eb_b, gin);

  EncArgs EA = { wefhh, webhh, gin, ench, encout, bar + TAG_E };
  hipLaunchKernelGGL(k_encoder, dim3(64), dim3(256), 0, stream, EA);

  DecArgs DA = { dec_embed, wattn, attn_b, encout, wcomb, comb_b,
                 wdih, d_b, wout8, wdhh8, out_b,
                 dech, hout8, hh, cat2, comb, pmax, psum, pidx, logz, out,
                 bar };
  hipLaunchKernelGGL(k_decoder, dim3(256), dim3(512), 0, stream, DA);

  hipLaunchKernelGGL(k_fixup, dim3(2048), dim3(256), 0, stream, out, logz);
}

// Round 18
// 4801.357 us; speedup vs baseline: 1.1150x; 1.1150x over previous
//
#include <hip/hip_runtime.h>
#include <hip/hip_bf16.h>
#include <string.h>

typedef __bf16 bf16;
typedef __attribute__((ext_vector_type(8))) __bf16 bf16x8;
typedef __attribute__((ext_vector_type(2))) __bf16 bf16x2;
typedef __attribute__((ext_vector_type(4))) float  f32x4;
typedef unsigned long long u64;
typedef unsigned char u8;

#define DEV __device__ __forceinline__

constexpr int V = 32000, E = 512, H = 512, L = 64, NB = 32, H2 = 1024, T = 64, SOS = 127;
constexpr int GE = 4 * H;
constexpr int NBLK = 256;        // decoder blocks; per-block logits partials

// ---- ws layout (bytes) ----
constexpr size_t OFF_GIN    = 0;                                  // f32 [2][T][NB][GE]
constexpr size_t SZ_GIN     = (size_t)2*T*NB*GE*4;
constexpr size_t OFF_ENCOUT = OFF_GIN + SZ_GIN;                   // bf16 [NB][L][H2]
constexpr size_t SZ_ENCOUT  = (size_t)NB*L*H2*2;
constexpr size_t OFF_ENCH   = OFF_ENCOUT + SZ_ENCOUT;             // bf16 [2][2][NB][H]
constexpr size_t SZ_ENCH    = (size_t)2*2*NB*H*2;
constexpr size_t OFF_DECH   = OFF_ENCH + SZ_ENCH;                 // bf16 [2][NB][H2]
constexpr size_t SZ_DECH    = (size_t)2*NB*H2*2;
constexpr size_t OFF_CAT2   = OFF_DECH + SZ_DECH;                 // bf16 [NB][2*H2]
constexpr size_t SZ_CAT2    = (size_t)NB*2*H2*2;
constexpr size_t OFF_COMB   = OFF_CAT2 + SZ_CAT2;                 // bf16 [NB][H2]
constexpr size_t SZ_COMB    = (size_t)NB*H2*2;
constexpr size_t OFF_HH     = OFF_COMB + SZ_COMB;                 // f32 [NB][4*H2]
constexpr size_t SZ_HH      = (size_t)NB*4*H2*4;
constexpr size_t OFF_PMAX   = OFF_HH + SZ_HH;                     // f32 [2][NBLK][NB] parity
constexpr size_t SZ_P       = (size_t)2*NBLK*NB*4;
constexpr size_t OFF_PSUM   = OFF_PMAX + SZ_P;
constexpr size_t OFF_PIDX   = OFF_PSUM + SZ_P;
constexpr size_t OFF_LOGZ   = OFF_PIDX + SZ_P;                    // f32 [T][NB]
constexpr size_t SZ_LOGZ    = (size_t)T*NB*4;
constexpr size_t OFF_WEFIH  = OFF_LOGZ + SZ_LOGZ;                 // bf16 [4H][E]
constexpr size_t SZ_WENC    = (size_t)GE*E*2;
constexpr size_t OFF_WEFHH  = OFF_WEFIH + SZ_WENC;
constexpr size_t OFF_WEBIH  = OFF_WEFHH + SZ_WENC;
constexpr size_t OFF_WEBHH  = OFF_WEBIH + SZ_WENC;
constexpr size_t OFF_WCOMB  = OFF_WEBHH + SZ_WENC;                // bf16 [H2][2*H2]
constexpr size_t SZ_WCOMB   = (size_t)H2*2*H2*2;
constexpr size_t OFF_WDIH   = OFF_WCOMB + SZ_WCOMB;               // bf16 [4*H2][H2]
constexpr size_t SZ_WDEC    = (size_t)4*H2*H2*2;
constexpr size_t OFF_WDHH   = OFF_WDIH + SZ_WDEC;                 // (unused now)
constexpr size_t OFF_WOUT   = OFF_WDHH + SZ_WDEC;                 // fp8 region (reuse 64MB)
constexpr size_t OFF_WOUT8  = OFF_WOUT;                           // u8 [V][1024] swizzled
constexpr size_t SZ_WOUT8   = (size_t)V*1024;
constexpr size_t OFF_WDHH8  = OFF_WOUT8 + SZ_WOUT8;               // u8 [4096][1024] swizzled
constexpr size_t SZ_WOUT    = (size_t)V*H2*2;
constexpr size_t OFF_WATTN  = OFF_WOUT + SZ_WOUT;                 // bf16 [L][2*H2]
constexpr size_t SZ_WATTN   = (size_t)L*2*H2*2;
constexpr size_t OFF_EMB2   = OFF_WATTN + SZ_WATTN;               // bf16 [T*NB][E]
constexpr size_t SZ_EMB2    = (size_t)T*NB*E*2;
constexpr size_t OFF_BAR    = OFF_EMB2 + SZ_EMB2;
// dataflow epoch tags (ints, 128B apart):
//  PT[256] @0, C2T[32] @8192, CBT[64] @9216, HT[64] @11264, ET[64] @13312
constexpr int TAG_PT = 0, TAG_C2 = 8192, TAG_CB = 9216, TAG_H = 11264, TAG_E = 13312;
constexpr int BAR_INTS = 15360;
constexpr size_t OFF_H8 = OFF_BAR + 131072;                       // u8 [32][1024] (h fp8)

// ---- decoder shared-memory layout ----
// Tiles 0-6 fixed at [0, 114688). ABC scratch overlaps SM_HL's 32KB region
// [114688, 147456): catF/red*/scr are live only in phases A-C; SM_HL (h
// staging + D reduce scratch) is live only in phase D. Strict temporal reuse.
constexpr int SM_HL   = 114688;   // u8 [32][1024] swizzled h fp8 / D reduce scratch
constexpr int SM_CATF = 114688;   // f32[2048]  -> ends 122880
constexpr int SM_REDM = 122880;   // f32[512]   -> ends 124928
constexpr int SM_REDS = 124928;   // f32[512]   -> ends 126976
constexpr int SM_REDI = 126976;   // int[512]   -> ends 129024
constexpr int SM_SCR  = 129024;   // f32[4096]  -> ends 145408
constexpr int SM_BYTES = 147456;

DEV f32x4 mfma16(bf16x8 a, bf16x8 b, f32x4 c) {
  return __builtin_amdgcn_mfma_f32_16x16x32_bf16(a, b, c, 0, 0, 0);
}
DEV f32x4 mfma8(long a, long b, f32x4 c) {
  return __builtin_amdgcn_mfma_f32_16x16x32_fp8_fp8(a, b, c, 0, 0, 0);
}
DEV float sigm(float x) { return 1.f / (1.f + __expf(-x)); }
DEV bf16x8 ld8(const bf16* p) { return *(const bf16x8*)p; }

// ---------- device-scope (uncached) accessors for cross-block data ----------
union U16 { u64 u[2]; bf16x8 v8; f32x4 f4; };
union U4  { unsigned int u; bf16x2 v2; float f; };

DEV bf16x8 ld8_dev(const bf16* p) {
  U16 r;
  r.u[0] = __hip_atomic_load((const u64*)p,       __ATOMIC_RELAXED, __HIP_MEMORY_SCOPE_AGENT);
  r.u[1] = __hip_atomic_load((const u64*)(p + 4), __ATOMIC_RELAXED, __HIP_MEMORY_SCOPE_AGENT);
  return r.v8;
}
DEV void st8_dev(bf16* p, bf16x8 v) {
  U16 r; r.v8 = v;
  __hip_atomic_store((u64*)p,       r.u[0], __ATOMIC_RELAXED, __HIP_MEMORY_SCOPE_AGENT);
  __hip_atomic_store((u64*)(p + 4), r.u[1], __ATOMIC_RELAXED, __HIP_MEMORY_SCOPE_AGENT);
}
DEV void st16f_dev(float* p, f32x4 v) {
  U16 r; r.f4 = v;
  __hip_atomic_store((u64*)p,       r.u[0], __ATOMIC_RELAXED, __HIP_MEMORY_SCOPE_AGENT);
  __hip_atomic_store((u64*)(p + 2), r.u[1], __ATOMIC_RELAXED, __HIP_MEMORY_SCOPE_AGENT);
}
DEV float ldf_dev(const float* p) {
  return __hip_atomic_load(p, __ATOMIC_RELAXED, __HIP_MEMORY_SCOPE_AGENT);
}
DEV void stf_dev(float* p, float v) {
  __hip_atomic_store(p, v, __ATOMIC_RELAXED, __HIP_MEMORY_SCOPE_AGENT);
}
DEV int ldi_dev(const int* p) {
  return __hip_atomic_load(p, __ATOMIC_RELAXED, __HIP_MEMORY_SCOPE_AGENT);
}
DEV void sti_dev(int* p, int v) {
  __hip_atomic_store(p, v, __ATOMIC_RELAXED, __HIP_MEMORY_SCOPE_AGENT);
}
DEV void stb_dev(bf16* p, float x) {
  bf16 h = (bf16)x; unsigned short s; memcpy(&s, &h, 2);
  __hip_atomic_store((unsigned short*)p, s, __ATOMIC_RELAXED, __HIP_MEMORY_SCOPE_AGENT);
}
DEV void st2b_dev(bf16* p, bf16x2 v) {
  U4 r; r.v2 = v;
  __hip_atomic_store((unsigned int*)p, r.u, __ATOMIC_RELAXED, __HIP_MEMORY_SCOPE_AGENT);
}
DEV void stb8_dev(u8* p, u8 v) {
  __hip_atomic_store(p, v, __ATOMIC_RELAXED, __HIP_MEMORY_SCOPE_AGENT);
}
DEV u64 ldu64_dev(const u8* p) {
  return __hip_atomic_load((const u64*)p, __ATOMIC_RELAXED, __HIP_MEMORY_SCOPE_AGENT);
}

// ---------- dataflow epoch tags: single-hop producer->consumer sync.
DEV void tpub(int* tags, int slot, int ep) {
  __syncthreads();
  if (threadIdx.x == 0)
    sti_dev(tags + slot*32, ep);
}
DEV void twait(int* tags, int n, int ep) {
  if ((int)threadIdx.x < n)
    while (ldi_dev(tags + threadIdx.x*32) < ep)
      __builtin_amdgcn_s_sleep(1);
  asm volatile("" ::: "memory");
  __syncthreads();
}

// --------------------------------------- one-shot f32 -> bf16 conversions
struct ConvJobs { const float* src[7]; bf16* dst[7]; long n8[7]; };

__global__ __launch_bounds__(256) void k_convert_all(ConvJobs J) {
  long i0 = (long)blockIdx.x * 256 + threadIdx.x;
  long stride = (long)gridDim.x * 256;
  for (int j = 0; j < 7; ++j) {
    const float* __restrict__ src = J.src[j];
    bf16* __restrict__ dst = J.dst[j];
    long n8 = J.n8[j];
    for (long g = i0; g < n8; g += stride) {
      long o = g * 8;
      float4 a = *(const float4*)(src + o);
      float4 b = *(const float4*)(src + o + 4);
      bf16x8 v;
      v[0]=(bf16)a.x; v[1]=(bf16)a.y; v[2]=(bf16)a.z; v[3]=(bf16)a.w;
      v[4]=(bf16)b.x; v[5]=(bf16)b.y; v[6]=(bf16)b.z; v[7]=(bf16)b.w;
      *(bf16x8*)(dst + o) = v;
    }
  }
}

// ---- f32 -> fp8 e4m3 (x8 scale), XOR-swizzled 16B granules ----
__global__ __launch_bounds__(256) void k_conv_fp8(const float* __restrict__ wsrc,
                                                  const float* __restrict__ hsrc,
                                                  u8* __restrict__ wdst,
                                                  u8* __restrict__ hdst) {
  const long G1 = (long)V*64, G2 = (long)4096*64;
  for (long id = (long)blockIdx.x*256 + threadIdx.x; id < G1 + G2;
       id += (long)gridDim.x*256) {
    const float* s; u8* d; long n, g;
    if (id < G1) { n = id >> 6; g = id & 63; s = wsrc + n*1024 + g*16;
                   d = wdst + n*1024 + ((g ^ (n & 7)) << 4); }
    else { long j = id - G1; n = j >> 6; g = j & 63; s = hsrc + n*1024 + g*16;
           d = hdst + n*1024 + ((g ^ (n & 7)) << 4); }
    unsigned int wv[4];
#pragma unroll
    for (int q = 0; q < 4; ++q) {
      float4 f = *(const float4*)(s + q*4);
      int lo = __builtin_amdgcn_cvt_pk_fp8_f32(f.x*8.f, f.y*8.f, 0, false);
      int hi = __builtin_amdgcn_cvt_pk_fp8_f32(f.z*8.f, f.w*8.f, 0, false);
      wv[q] = (lo & 0xFFFF) | (hi << 16);
    }
    *(uint4*)d = make_uint4(wv[0], wv[1], wv[2], wv[3]);
  }
}

__global__ __launch_bounds__(256) void k_gather_emb(const int* __restrict__ x,
                                                    const float* __restrict__ embed,
                                                    bf16* __restrict__ emb2) {
  int gid = blockIdx.x * 256 + threadIdx.x;
  int m = gid >> 6, k8 = (gid & 63) * 8;
  int b = m & 31, t = m >> 5;
  int tok = x[b * L + t];
  const float* src = embed + (long)tok * E + k8;
  float4 a = *(const float4*)src;
  float4 c = *(const float4*)(src + 4);
  bf16x8 v;
  v[0]=(bf16)a.x; v[1]=(bf16)a.y; v[2]=(bf16)a.z; v[3]=(bf16)a.w;
  v[4]=(bf16)c.x; v[5]=(bf16)c.y; v[6]=(bf16)c.z; v[7]=(bf16)c.w;
  *(bf16x8*)(emb2 + (long)m * E + k8) = v;
}

__global__ __launch_bounds__(256) void k_init(bf16* ench, bf16* dech, float* hh,
                                              int* bar) {
  int i = blockIdx.x * 256 + threadIdx.x;          // grid 512
  hh[i] = 0.f;
  if (i < 2*NB*H)  ench[i] = (bf16)0.f;
  if (i < NB*H2)   dech[i] = (bf16)0.f;
  if (i < BAR_INTS) bar[i] = 0;
}

// ------------------------------------------- encoder input gates (both dirs)
__global__ __launch_bounds__(256) void k_enc_ingemm(
    const bf16* __restrict__ emb2,
    const bf16* __restrict__ fWih, const float* __restrict__ fB,
    const bf16* __restrict__ bWih, const float* __restrict__ bB,
    float* __restrict__ gin)
{
  int wid  = blockIdx.x * 4 + (threadIdx.x >> 6);
  int lane = threadIdx.x & 63;
  int dir  = wid >> 11;
  int w2   = wid & 2047;
  int m0   = (w2 >> 5) * 32;
  int n0   = (w2 & 31) * 64;
  const bf16*  Wih  = dir ? bWih : fWih;
  const float* Bias = dir ? bB : fB;
  int col = lane & 15, kq = lane >> 4, r4 = kq * 4;

  const bf16* arow[4];
#pragma unroll
  for (int nt = 0; nt < 4; ++nt) arow[nt] = Wih + (long)(n0 + nt*16 + col)*E + kq*8;
  const bf16* brow[2];
#pragma unroll
  for (int mt = 0; mt < 2; ++mt) brow[mt] = emb2 + (long)(m0 + mt*16 + col)*E + kq*8;

  f32x4 acc[2][4] = {};
  for (int kk = 0; kk < E/32; ++kk) {
    bf16x8 a[4], bv[2];
#pragma unroll
    for (int nt = 0; nt < 4; ++nt) a[nt] = ld8(arow[nt] + kk*32);
#pragma unroll
    for (int mt = 0; mt < 2; ++mt) bv[mt] = ld8(brow[mt] + kk*32);
#pragma unroll
    for (int mt = 0; mt < 2; ++mt)
#pragma unroll
      for (int nt = 0; nt < 4; ++nt)
        acc[mt][nt] = mfma16(a[nt], bv[mt], acc[mt][nt]);
  }
#pragma unroll
  for (int mt = 0; mt < 2; ++mt) {
    int m = m0 + mt*16 + col;
    int b = m & 31, t = m >> 5;
    float* gp = gin + ((long)(dir*T + t)*NB + b)*GE;
#pragma unroll
    for (int nt = 0; nt < 4; ++nt) {
      int nb = n0 + nt*16 + r4;
      f32x4 v = acc[mt][nt];
      float4 o;
      o.x = v[0] + Bias[nb+0];
      o.y = v[1] + Bias[nb+1];
      o.z = v[2] + Bias[nb+2];
      o.w = v[3] + Bias[nb+3];
      *(float4*)(gp + nb) = o;
    }
  }
}

// ============================ persistent encoder =========================
struct EncArgs {
  const bf16* fWhh; const bf16* bWhh; const float* gin;
  bf16* ench; bf16* encout; int* etag;
};

__global__ __launch_bounds__(256, 1) void k_encoder(EncArgs A) {
  __shared__ float lds[4][16][32];
  int tid = threadIdx.x, w = tid >> 6, lane = tid & 63;
  int dir = blockIdx.x >> 5, j0 = (blockIdx.x & 31) * 16;
  int col = lane & 15, kq = lane >> 4, r4 = kq*4;
  const bf16* Whh = dir ? A.bWhh : A.fWhh;
  const bf16* arow = Whh + (long)(w*H + j0 + col)*H + kq*8;
  int* myTags = A.etag + dir*32*32;      // 32 same-dir tag lines
  float creg0 = 0.f, creg1 = 0.f;

  for (int t = 0; t < T; ++t) {
    if (t > 0) twait(myTags, 32, t);
    const bf16* hbase = A.ench + (t&1)*(2*NB*H) + dir*(NB*H);
    bf16*       hout  = A.ench + ((t&1)^1)*(2*NB*H) + dir*(NB*H);
    const bf16* b0 = hbase + col*H + kq*8;
    const bf16* b1 = hbase + (16+col)*H + kq*8;
    f32x4 a0 = {}, a1 = {};
    for (int kk = 0; kk < H/32; ++kk) {
      bf16x8 a = ld8(arow + kk*32);
      a0 = mfma16(a, ld8_dev(b0 + kk*32), a0);
      a1 = mfma16(a, ld8_dev(b1 + kk*32), a1);
    }
#pragma unroll
    for (int r = 0; r < 4; ++r) { lds[w][r4+r][col] = a0[r]; lds[w][r4+r][16+col] = a1[r]; }
    __syncthreads();
    const float* gp = A.gin + (long)(dir*T + t)*NB*GE;
    {
      int jj = tid >> 5, b = tid & 31, j = j0 + jj;
      const float* g4 = gp + (long)b*GE;
      float i_ = sigm(lds[0][jj][b] + g4[0*H + j]);
      float f_ = sigm(lds[1][jj][b] + g4[1*H + j]);
      float g_ = tanhf(lds[2][jj][b] + g4[2*H + j]);
      float o_ = sigm(lds[3][jj][b] + g4[3*H + j]);
      float c2 = f_*creg0 + i_*g_; creg0 = c2;
      float hv = o_*tanhf(c2);
      stb_dev(hout + b*H + j, hv);
      A.encout[((long)b*L + t)*H2 + dir*H + j] = (bf16)hv;
    }
    {
      int idx = tid + 256, jj = idx >> 5, b = idx & 31, j = j0 + jj;
      const float* g4 = gp + (long)b*GE;
      float i_ = sigm(lds[0][jj][b] + g4[0*H + j]);
      float f_ = sigm(lds[1][jj][b] + g4[1*H + j]);
      float g_ = tanhf(lds[2][jj][b] + g4[2*H + j]);
      float o_ = sigm(lds[3][jj][b] + g4[3*H + j]);
      float c2 = f_*creg1 + i_*g_; creg1 = c2;
      float hv = o_*tanhf(c2);
      stb_dev(hout + b*H + j, hv);
      A.encout[((long)b*L + t)*H2 + dir*H + j] = (bf16)hv;
    }
    tpub(myTags, blockIdx.x & 31, t + 1);
  }
}

// ============================ persistent decoder (512 thr) ================
struct DecArgs {
  const float* dec_embed; const bf16* wattn; const float* attn_b;
  const bf16* encout;
  const bf16* wcomb; const float* comb_b;
  const bf16* wdih; const float* db;
  const u8* wout8; const u8* wdhh8; const float* outb;
  bf16* dech; u8* hout8; float* hh; bf16* cat2; bf16* comb;
  float* pmax; float* psum; int* pidx; float* logz; float* out;
  int* tags;
};

__global__ __launch_bounds__(512, 1) void k_decoder(DecArgs A) {
  __shared__ __attribute__((aligned(16))) char smem[SM_BYTES];
  __shared__ float aw[64];
  __shared__ int   stok;
  float* catF = (float*)(smem + SM_CATF);
  float* redm = (float*)(smem + SM_REDM);
  float* reds = (float*)(smem + SM_REDS);
  int*   redi = (int*)  (smem + SM_REDI);
  float* scr  = (float*)(smem + SM_SCR);

  int* PT  = A.tags + TAG_PT;
  int* C2T = A.tags + TAG_C2;
  int* CBT = A.tags + TAG_CB;
  int* HT  = A.tags + TAG_H;

  int tid = threadIdx.x, bid = blockIdx.x;
  int w = tid >> 6, lane = tid & 63;
  int col = lane & 15, kq = lane >> 4, r4 = kq*4;
  float creg = 0.f;                    // cell state (blocks 0..63)

  // -------- tile ownership: blocks 0-47: 8 tiles; 48-255: 9 tiles --------
  int ntot = (bid < 48) ? 8 : 9;
  int tstart = (bid < 48) ? bid*8 : 384 + 9*(bid - 48);
  const int nlds = 7;                  // all blocks keep 7 tiles in LDS

  // -------- one-time: fill LDS weight tiles (fp8, pre-swizzled global) ---
  for (int i = 0; i < nlds; ++i) {
    int tn = tstart + i;
    const u8* src = (tn < 2000) ? A.wout8 + (long)tn*16384
                                : A.wdhh8 + (long)(tn - 2000)*16384;
#pragma unroll
    for (int rr = 0; rr < 2; ++rr) {
      int flat = rr*8192 + w*1024 + lane*16;
      __builtin_amdgcn_global_load_lds(
          (const __attribute__((address_space(1))) void*)(src + flat),
          (__attribute__((address_space(3))) void*)(smem + i*16384 + rr*8192 + w*1024),
          16, 0, 0);
    }
  }
  asm volatile("s_waitcnt vmcnt(0)" ::: "memory");
  __syncthreads();

  for (int t = 0; t < T; ++t) {
    const bf16* hin  = A.dech + (t&1)*(NB*H2);
    bf16*       hout = A.dech + ((t&1)^1)*(NB*H2);
    float* pmaxP = A.pmax + ((t&1)^1)*NBLK*32;     // partials of step t-1
    float* psumP = A.psum + ((t&1)^1)*NBLK*32;
    int*   pidxP = A.pidx + ((t&1)^1)*NBLK*32;

    // ---------------- phase A: argmax(t-1) + attention + cat2 -------------
    if (bid < NB) {
      int b = bid;
      if (t > 0) {
        twait(PT, NBLK, t);
        // wave-shuffle argmax reduce: threads 0-255 (waves 0-3) hold partials
        float m = -1e30f, s = 0.f; int id = 0;
        if (tid < 256) {
          m  = ldf_dev(pmaxP + tid*32 + b);
          s  = ldf_dev(psumP + tid*32 + b);
          id = ldi_dev(pidxP + tid*32 + b);
#pragma unroll
          for (int off = 1; off < 64; off <<= 1) {
            float om = __shfl_xor(m, off);
            float os = __shfl_xor(s, off);
            int   oi = __shfl_xor(id, off);
            s += os;
            if (om > m || (om == m && oi < id)) { m = om; id = oi; }
          }
          if (lane == 0) { redm[w] = m; reds[w] = s; redi[w] = id; }
        }
        __syncthreads();
        if (tid == 0) {
          float mm = redm[0]; int ii2 = redi[0];
          float ss = reds[0] + reds[1] + reds[2] + reds[3];
#pragma unroll
          for (int q = 1; q < 4; ++q) {
            if (redm[q] > mm || (redm[q] == mm && redi[q] < ii2)) { mm = redm[q]; ii2 = redi[q]; }
          }
          A.logz[(t-1)*32 + b] = logf(ss);
          stok = ii2;
        }
      } else if (tid == 0) stok = SOS;
      __syncthreads();
      int tok = stok;

      const float* erow = A.dec_embed + (long)tok*H2;
      bf16* c2row = A.cat2 + (long)b*(2*H2);
      if (tid < 128) {
        int o = tid*8;
        float4 a = *(const float4*)(erow + o);
        float4 c = *(const float4*)(erow + o + 4);
        catF[o+0]=a.x; catF[o+1]=a.y; catF[o+2]=a.z; catF[o+3]=a.w;
        catF[o+4]=c.x; catF[o+5]=c.y; catF[o+6]=c.z; catF[o+7]=c.w;
        bf16x8 v;
        v[0]=(bf16)a.x; v[1]=(bf16)a.y; v[2]=(bf16)a.z; v[3]=(bf16)a.w;
        v[4]=(bf16)c.x; v[5]=(bf16)c.y; v[6]=(bf16)c.z; v[7]=(bf16)c.w;
        st8_dev(c2row + o, v);
      } else if (tid < 256) {
        int o = (tid - 128)*8;
        bf16x8 hv = ld8_dev(hin + (long)b*H2 + o);
#pragma unroll
        for (int e = 0; e < 8; ++e) catF[H2 + o + e] = (float)hv[e];
      }
      __syncthreads();

      {  // scores: 8 threads per l, K=256 each
        int l = tid >> 3, q = tid & 7;
        const bf16*  wrow = A.wattn + (long)l*(2*H2) + q*256;
        const float* crow = catF + q*256;
        float sacc = 0.f;
        for (int k = 0; k < 256; k += 8) {
          bf16x8 wv = ld8(wrow + k);
#pragma unroll
          for (int e = 0; e < 8; ++e) sacc += (float)wv[e] * crow[k+e];
        }
        sacc += __shfl_xor(sacc, 1);
        sacc += __shfl_xor(sacc, 2);
        sacc += __shfl_xor(sacc, 4);
        if (q == 0) aw[l] = sacc + A.attn_b[l];
      }
      __syncthreads();

      if (tid < 64) {  // softmax over L
        float v = aw[tid];
        float m = v;
#pragma unroll
        for (int off = 1; off < 64; off <<= 1) m = fmaxf(m, __shfl_xor(m, off));
        float p = __expf(v - m);
        float s = p;
#pragma unroll
        for (int off = 1; off < 64; off <<= 1) s += __shfl_xor(s, off);
        aw[tid] = p / s;
      }
      __syncthreads();

      {  // ctx: 4 l-groups x 128 threads x bf16x8
        int grp = tid >> 7, jt = tid & 127;
        int j8 = jt * 8;
        const bf16* eo = A.encout + (long)b*L*H2 + j8;
        float acc[8] = {};
        for (int l = grp*16; l < grp*16 + 16; ++l) {
          float a = aw[l];
          bf16x8 v = ld8(eo + (long)l*H2);
#pragma unroll
          for (int e = 0; e < 8; ++e) acc[e] += a*(float)v[e];
        }
#pragma unroll
        for (int e = 0; e < 8; ++e) scr[grp*1024 + j8 + e] = acc[e];
      }
      __syncthreads();
      {
        int j2 = tid * 2;
        bf16x2 o;
#pragma unroll
        for (int e = 0; e < 2; ++e) {
          int j = j2 + e;
          o[e] = (bf16)(scr[j] + scr[1024+j] + scr[2048+j] + scr[3072+j]);
        }
        st2b_dev(c2row + H2 + j2, o);
      }
      tpub(C2T, bid, t + 1);
    }

    // ---------------- phase B: comb = relu(cat2@Wc.T + b) ----------------
    if (bid < 64) {
      twait(C2T, 32, t + 1);
      int n0 = bid * 16;
      const bf16* arow = A.wcomb + (long)(n0 + col)*(2*H2) + w*256 + kq*8;
      const bf16* b0 = A.cat2 + (long)col*(2*H2) + w*256 + kq*8;
      const bf16* b1 = A.cat2 + (long)(16+col)*(2*H2) + w*256 + kq*8;
      f32x4 a0 = {}, a1 = {};
      for (int kk = 0; kk < 8; ++kk) {
        bf16x8 a = ld8(arow + kk*32);
        a0 = mfma16(a, ld8_dev(b0 + kk*32), a0);
        a1 = mfma16(a, ld8_dev(b1 + kk*32), a1);
      }
#pragma unroll
      for (int r = 0; r < 4; ++r) {
        scr[(w*2+0)*256 + (r4+r)*16 + col] = a0[r];
        scr[(w*2+1)*256 + (r4+r)*16 + col] = a1[r];
      }
      __syncthreads();
      {
        int r = tid >> 5, b = tid & 31;
        int bt = b >> 4, cb = b & 15;
        float v = 0.f;
#pragma unroll
        for (int g = 0; g < 8; ++g) v += scr[(g*2+bt)*256 + r*16 + cb];
        v += A.comb_b[n0 + r];
        stb_dev(A.comb + (long)b*H2 + n0 + r, fmaxf(v, 0.f));
      }
      tpub(CBT, bid, t + 1);
    }

    // ---------------- phase C: LSTM cell ----------------
    if (bid < 64) {
      twait(CBT, 64, t + 1);
      int j0 = bid * 16;
      int g = w >> 1, half = w & 1;
      const bf16* arow = A.wdih + (long)(g*H2 + j0 + col)*H2 + half*512 + kq*8;
      const bf16* b0 = A.comb + (long)col*H2 + half*512 + kq*8;
      const bf16* b1 = A.comb + (long)(16+col)*H2 + half*512 + kq*8;
      f32x4 a0 = {}, a1 = {};
      for (int kk = 0; kk < 16; ++kk) {
        bf16x8 a = ld8(arow + kk*32);
        a0 = mfma16(a, ld8_dev(b0 + kk*32), a0);
        a1 = mfma16(a, ld8_dev(b1 + kk*32), a1);
      }
#pragma unroll
      for (int r = 0; r < 4; ++r) {
        scr[(w*2+0)*256 + (r4+r)*16 + col] = a0[r];
        scr[(w*2+1)*256 + (r4+r)*16 + col] = a1[r];
      }
      __syncthreads();
      {
        int jj = tid >> 5, b = tid & 31, j = j0 + jj;
        int bt = b >> 4, cb = b & 15;
#define GV(gg) (scr[((2*(gg)+0)*2+bt)*256 + jj*16 + cb] + scr[((2*(gg)+1)*2+bt)*256 + jj*16 + cb] \
                + A.db[(gg)*H2 + j] + ldf_dev(A.hh + (long)b*(4*H2) + (gg)*H2 + j))
        float i_ = sigm(GV(0));
        float f_ = sigm(GV(1));
        float g_ = tanhf(GV(2));
        float o_ = sigm(GV(3));
#undef GV
        float c2 = f_*creg + i_*g_; creg = c2;
        float hv = o_*tanhf(c2);
        stb_dev(hout + b*H2 + j, hv);
        int q8 = __builtin_amdgcn_cvt_pk_fp8_f32(hv*16.f, hv*16.f, 0, false);
        stb8_dev(A.hout8 + b*1024 + j, (u8)(q8 & 0xFF));
      }
      tpub(HT, bid, t + 1);
    }

    // ----- phase D: logits/hh from LDS-resident fp8 weights ---------------
    {
      twait(HT, 64, t + 1);
      float* pmaxW = A.pmax + (t&1)*NBLK*32;       // partials of step t
      float* psumW = A.psum + (t&1)*NBLK*32;
      int*   pidxW = A.pidx + (t&1)*NBLK*32;

      // stage h fp8 -> LDS (swizzled); overwrites ABC scratch (dead now)
#pragma unroll
      for (int k2 = 0; k2 < 4; ++k2) {
        int id = k2*512 + tid;
        int r = id >> 6, g = id & 63;
        const u8* sp = A.hout8 + r*1024 + g*16;
        u64 lo = ldu64_dev(sp);
        u64 hi = ldu64_dev(sp + 8);
        char* dp = smem + SM_HL + r*1024 + ((g ^ (r & 7)) << 4);
        *(u64*)dp = lo; *(u64*)(dp + 8) = hi;
      }
      __syncthreads();

      float pm[2] = {-1e30f, -1e30f};
      float ps[2] = {0.f, 0.f};
      int  pid[2] = {0, 0};

      for (int ii = 0; ii < 2; ++ii) {
        if (ii == 1 && (w != 0 || ntot < 9)) break;
        int ti = (ii == 0) ? w : 8;
        int tn = tstart + ti;
        f32x4 acc0 = {}, acc1 = {};
        if (ti < nlds) {
          const char* Ab = smem + ti*16384 + col*1024;
          const char* Hb = smem + SM_HL + col*1024;
#pragma unroll 8
          for (int ks = 0; ks < 32; ++ks) {
            int off = (((ks*2 + (kq>>1)) ^ (col & 7)) << 4) + (kq & 1)*8;
            long a  = *(const long*)(Ab + off);
            long b0 = *(const long*)(Hb + off);
            long b1 = *(const long*)(Hb + 16*1024 + off);
            acc0 = mfma8(a, b0, acc0);
            acc1 = mfma8(a, b1, acc1);
          }
        } else {
          // streamed tiles: UNCACHED reads (bypass L2 -> no thrash of ABC set)
          const u8* Ab = ((tn < 2000) ? A.wout8 + (long)tn*16384
                                      : A.wdhh8 + (long)(tn - 2000)*16384) + col*1024;
          const char* Hb = smem + SM_HL + col*1024;
#pragma unroll 8
          for (int ks = 0; ks < 32; ++ks) {
            int off = (((ks*2 + (kq>>1)) ^ (col & 7)) << 4) + (kq & 1)*8;
            long a  = (long)ldu64_dev(Ab + off);
            long b0 = *(const long*)(Hb + off);
            long b1 = *(const long*)(Hb + 16*1024 + off);
            acc0 = mfma8(a, b0, acc0);
            acc1 = mfma8(a, b1, acc1);
          }
        }
        if (tn < 2000) {
          int nb = tn*16 + kq*4;
#pragma unroll
          for (int bt = 0; bt < 2; ++bt) {
            int b = col + bt*16;
            f32x4 v = bt ? acc1 : acc0;
            f32x4 o;
#pragma unroll
            for (int r = 0; r < 4; ++r) {
              float xv = v[r]*0.0078125f + A.outb[nb + r];
              o[r] = xv;
              ps[bt] += __expf(xv);
              if (xv > pm[bt]) { pm[bt] = xv; pid[bt] = nb + r; }
            }
            __builtin_nontemporal_store(o, (f32x4*)(A.out + ((long)b*T + t)*V + nb));
          }
        } else {
          int nb = (tn - 2000)*16 + kq*4;
#pragma unroll
          for (int bt = 0; bt < 2; ++bt) {
            int b = col + bt*16;
            f32x4 v = bt ? acc1 : acc0;
#pragma unroll
            for (int r = 0; r < 4; ++r) v[r] *= 0.0078125f;
            st16f_dev(A.hh + (long)b*(4*H2) + nb, v);
          }
        }
      }
      // wave-level reduce
#pragma unroll
      for (int off = 16; off <= 32; off <<= 1) {
#pragma unroll
        for (int bt = 0; bt < 2; ++bt) {
          float om = __shfl_xor(pm[bt], off);
          float os = __shfl_xor(ps[bt], off);
          int   oi = __shfl_xor(pid[bt], off);
          ps[bt] += os;
          if (om > pm[bt] || (om == pm[bt] && oi < pid[bt])) { pm[bt] = om; pid[bt] = oi; }
        }
      }
      // cross-wave reduce to ONE per-block partial (reuse SM_HL after h reads)
      __syncthreads();
      float* dm = (float*)(smem + SM_HL);
      float* ds = dm + 256;
      int*   di = (int*)(ds + 256);
      if (lane < 16) {
#pragma unroll
        for (int bt = 0; bt < 2; ++bt) {
          int b = bt*16 + lane;
          dm[w*32 + b] = pm[bt];
          ds[w*32 + b] = ps[bt];
          di[w*32 + b] = pid[bt];
        }
      }
      __syncthreads();
      if (tid < 32) {
        int b = tid;
        float m = -1e30f, s = 0.f; int id = 0;
#pragma unroll
        for (int r = 0; r < 8; ++r) {
          float om = dm[r*32 + b]; int oi = di[r*32 + b];
          s += ds[r*32 + b];
          if (om > m || (om == m && oi < id)) { m = om; id = oi; }
        }
        stf_dev(pmaxW + bid*32 + b, m);
        stf_dev(psumW + bid*32 + b, s);
        sti_dev(pidxW + bid*32 + b, id);
      }
      tpub(PT, bid, t + 1);
    }
  }

  // final logZ (step T-1): partials parity (T-1)&1 = 1
  if (bid < NB) {
    twait(PT, NBLK, T);
    int b = bid;
    const float* psumP = A.psum + ((T-1)&1)*NBLK*32;
    float s = 0.f;
    if (tid < 256) {
      s = ldf_dev(psumP + tid*32 + b);
#pragma unroll
      for (int off = 1; off < 64; off <<= 1) s += __shfl_xor(s, off);
      if (lane == 0) reds[w] = s;
    }
    __syncthreads();
    if (tid == 0) A.logz[(T-1)*32 + b] = logf(reds[0] + reds[1] + reds[2] + reds[3]);
  }
}

// ------------------------- final: out[b][t][v] = raw_logit - logZ[t][b]
__global__ __launch_bounds__(256) void k_fixup(float* __restrict__ out,
                                               const float* __restrict__ logz)
{
  long i = (long)blockIdx.x * 256 + threadIdx.x;
  long stride = (long)gridDim.x * 256;
  long total = (long)NB * T * V / 4;
  for (long g = i; g < total; g += stride) {
    long flat = g * 4;
    long bt = flat / V;
    int tt = (int)(bt & 63), b = (int)(bt >> 6);
    float lz = logz[tt*32 + b];
    f32x4 v = *(const f32x4*)(out + flat);
    v[0] -= lz; v[1] -= lz; v[2] -= lz; v[3] -= lz;
    __builtin_nontemporal_store(v, (f32x4*)(out + flat));
  }
}

extern "C" void kernel_launch(void* const* d_in, const int* in_sizes, int n_in,
                              void* d_out, int out_size, void* d_ws, size_t ws_size,
                              hipStream_t stream)
{
  const int*   x         = (const int*)  d_in[0];
  const float* enc_embed = (const float*)d_in[1];
  const float* ef_Wih    = (const float*)d_in[2];
  const float* ef_Whh    = (const float*)d_in[3];
  const float* ef_b      = (const float*)d_in[4];
  const float* eb_Wih    = (const float*)d_in[5];
  const float* eb_Whh    = (const float*)d_in[6];
  const float* eb_b      = (const float*)d_in[7];
  const float* dec_embed = (const float*)d_in[8];
  const float* attn_W    = (const float*)d_in[9];
  const float* attn_b    = (const float*)d_in[10];
  const float* comb_W    = (const float*)d_in[11];
  const float* comb_b    = (const float*)d_in[12];
  const float* d_Wih     = (const float*)d_in[13];
  const float* d_Whh     = (const float*)d_in[14];
  const float* d_b       = (const float*)d_in[15];
  const float* out_W     = (const float*)d_in[16];
  const float* out_b     = (const float*)d_in[17];
  float* out = (float*)d_out;
  char* ws = (char*)d_ws;

  float* gin    = (float*)(ws + OFF_GIN);
  bf16*  encout = (bf16*) (ws + OFF_ENCOUT);
  bf16*  ench   = (bf16*) (ws + OFF_ENCH);
  bf16*  dech   = (bf16*) (ws + OFF_DECH);
  bf16*  cat2   = (bf16*) (ws + OFF_CAT2);
  bf16*  comb   = (bf16*) (ws + OFF_COMB);
  float* hh     = (float*)(ws + OFF_HH);
  float* pmax   = (float*)(ws + OFF_PMAX);
  float* psum   = (float*)(ws + OFF_PSUM);
  int*   pidx   = (int*)  (ws + OFF_PIDX);
  float* logz   = (float*)(ws + OFF_LOGZ);
  bf16*  wefih  = (bf16*) (ws + OFF_WEFIH);
  bf16*  wefhh  = (bf16*) (ws + OFF_WEFHH);
  bf16*  webih  = (bf16*) (ws + OFF_WEBIH);
  bf16*  webhh  = (bf16*) (ws + OFF_WEBHH);
  bf16*  wcomb  = (bf16*) (ws + OFF_WCOMB);
  bf16*  wdih   = (bf16*) (ws + OFF_WDIH);
  u8*    wout8  = (u8*)   (ws + OFF_WOUT8);
  u8*    wdhh8  = (u8*)   (ws + OFF_WDHH8);
  bf16*  wattn  = (bf16*) (ws + OFF_WATTN);
  bf16*  emb2   = (bf16*) (ws + OFF_EMB2);
  int*   bar    = (int*)  (ws + OFF_BAR);
  u8*    hout8  = (u8*)   (ws + OFF_H8);

  ConvJobs J;
  J.src[0]=ef_Wih; J.dst[0]=wefih; J.n8[0]=(long)GE*E/8;
  J.src[1]=ef_Whh; J.dst[1]=wefhh; J.n8[1]=(long)GE*H/8;
  J.src[2]=eb_Wih; J.dst[2]=webih; J.n8[2]=(long)GE*E/8;
  J.src[3]=eb_Whh; J.dst[3]=webhh; J.n8[3]=(long)GE*H/8;
  J.src[4]=comb_W; J.dst[4]=wcomb; J.n8[4]=(long)H2*2*H2/8;
  J.src[5]=d_Wih;  J.dst[5]=wdih;  J.n8[5]=(long)4*H2*H2/8;
  J.src[6]=attn_W; J.dst[6]=wattn; J.n8[6]=(long)L*2*H2/8;
  hipLaunchKernelGGL(k_convert_all, dim3(2048), dim3(256), 0, stream, J);
  hipLaunchKernelGGL(k_conv_fp8, dim3(2048), dim3(256), 0, stream,
                     out_W, d_Whh, wout8, wdhh8);
  hipLaunchKernelGGL(k_gather_emb, dim3(512), dim3(256), 0, stream, x, enc_embed, emb2);
  hipLaunchKernelGGL(k_init, dim3(512), dim3(256), 0, stream, ench, dech, hh, bar);
  hipLaunchKernelGGL(k_enc_ingemm, dim3(1024), dim3(256), 0, stream,
                     emb2, wefih, ef_b, webih, eb_b, gin);

  EncArgs EA = { wefhh, webhh, gin, ench, encout, bar + TAG_E };
  hipLaunchKernelGGL(k_encoder, dim3(64), dim3(256), 0, stream, EA);

  DecArgs DA = { dec_embed, wattn, attn_b, encout, wcomb, comb_b,
                 wdih, d_b, wout8, wdhh8, out_b,
                 dech, hout8, hh, cat2, comb, pmax, psum, pidx, logz, out,
                 bar };
  hipLaunchKernelGGL(k_decoder, dim3(256), dim3(512), 0, stream, DA);

  hipLaunchKernelGGL(k_fixup, dim3(2048), dim3(256), 0, stream, out, logz);
}